// Round 18
// baseline (405.208 us; speedup 1.0000x reference)
//
#include <hip/hip_runtime.h>

#define N_NODES 50000
#define N_EDGES 1600000
#define HID     128
#define N_GRAPHS 64

#define HB 200                            // hist slices (edge-position based)
#define EPB (N_EDGES / HB)                // 8000 edges per slice
#define HWORDS 12500                      // 50000 nodes packed u8 x4 per word
#define NPP 12500                         // dst nodes per fill pass
#define CWPP (NPP / 4)                    // 3125 cursor words per pass (u8)
#define NGRP 8                            // slice groups for 2-level scan
#define SPG (HB / NGRP)                   // 25 slices per group
#define NQ 4                              // src quarters (sort windows, 3.2MB < 4MB L2)
#define QN (N_NODES / NQ)                 // 12500 srcs per quarter

// workspace layout (4-byte words) — WS_END identical to the verified baseline.
#define WS_DEG   0u         // int[50000]
#define WS_BSUM  50000u     // int[256]
#define WS_BOFF  50256u     // int[256] (unused, layout stability)
#define WS_OFFS  50512u     // int[50000]
#define WS_INVD  100512u    // float[50000]
#define WS_CSR   150512u    // u16[1600000] (800K words); pool partials here after layers
#define WS_QOFF  950512u    // (unused; kept for layout stability)
#define WS_XB_B  1750512u   // uint[3200000]: hist(2.5M)+gsum during build; x ping B after
#define WS_GSUM  (WS_XB_B + 2500000u)     // uint[100000] scan-group totals (build only)
#define WS_XB_A  4950512u   // uint[3200000]: x ping buffer A (bf16 x2: 50000x128)
#define WS_WP    8150512u   // uint[49152] = packed W frags: 3 layers x 4096 uint4
#define WS_END   8199664u

typedef __attribute__((ext_vector_type(8))) short short8;
typedef __attribute__((ext_vector_type(4))) float floatx4;

// ---- bf16 helpers (raw, RN-even pack; fp32 math everywhere) ----
__device__ __forceinline__ float bf_lo(unsigned u) { return __uint_as_float(u << 16); }
__device__ __forceinline__ float bf_hi(unsigned u) { return __uint_as_float(u & 0xffff0000u); }
__device__ __forceinline__ unsigned bf_rn(float f) {
    unsigned u = __float_as_uint(f);
    unsigned r = ((u >> 16) & 1u) + 0x7fffu;
    return (u + r) >> 16;
}
__device__ __forceinline__ unsigned bf_pack(float lo, float hi) {
    return bf_rn(lo) | (bf_rn(hi) << 16);
}

// ---------------- prep+hist fused, 1024 threads ----------------
__global__ __launch_bounds__(1024) void k_prephist(const float4* __restrict__ x, uint2* __restrict__ o,
                                                   const float* __restrict__ Wn, const float* __restrict__ Wr,
                                                   uint4* __restrict__ wp, const int* __restrict__ ei,
                                                   unsigned* __restrict__ hist) {
    __shared__ unsigned sh[HWORDS];   // 50 KB (hist branch)
    if (blockIdx.x < 1563) {
        int i = blockIdx.x * 1024 + threadIdx.x;     // 1.6M float4 total
        if (i < 1600000) {
            float4 v = x[i];
            uint2 r;
            r.x = bf_pack(v.x, v.y);
            r.y = bf_pack(v.z, v.w);
            o[i] = r;
        }
    } else if (blockIdx.x < 1575) {
        int idx = (blockIdx.x - 1563) * 1024 + threadIdx.x;   // 12288 total
        int layer = idx >> 12;
        int rem = idx & 4095;
        int kb = rem >> 9;
        int n = (rem >> 2) & 127;
        int quad = rem & 3;
        float v[8];
#pragma unroll
        for (int j = 0; j < 8; j++) {
            int k = kb * 32 + quad * 8 + j;
            v[j] = (k < 128) ? Wn[layer * 16384 + k * 128 + n]
                             : Wr[layer * 16384 + (k - 128) * 128 + n];
        }
        uint4 r;
        r.x = bf_pack(v[0], v[1]);
        r.y = bf_pack(v[2], v[3]);
        r.z = bf_pack(v[4], v[5]);
        r.w = bf_pack(v[6], v[7]);
        wp[idx] = r;
    } else {
        const int hb = blockIdx.x - 1575;            // 0..199 hist slice
        for (int i = threadIdx.x; i < HWORDS; i += 1024) sh[i] = 0;
        __syncthreads();
        const int e0 = hb * EPB;
        for (int i = threadIdx.x; i < EPB; i += 1024) {
            int d = __builtin_nontemporal_load(ei + N_EDGES + e0 + i);
            atomicAdd(&sh[d >> 2], 1u << ((d & 3) << 3));
        }
        __syncthreads();
        unsigned* hp = hist + (size_t)hb * HWORDS;
        for (int i = threadIdx.x; i < HWORDS; i += 1024) hp[i] = sh[i];
    }
}

// ---------------- CSR build ----------------

// Stage 2a: group-local exclusive scan over 25 slices (in place) + per-group totals.
__global__ __launch_bounds__(256) void k_scanb1(unsigned* __restrict__ hist, unsigned* __restrict__ gsum) {
    int wb = blockIdx.x % 49;
    int g = blockIdx.x / 49;
    int w = wb * 256 + threadIdx.x;
    if (w >= HWORDS) return;
    size_t base = (size_t)(g * SPG) * HWORDS + w;
    unsigned run = 0;
#pragma unroll 5
    for (int b = 0; b < SPG; ++b) {
        unsigned u = hist[base + (size_t)b * HWORDS];
        hist[base + (size_t)b * HWORDS] = run;
        run += u;
    }
    gsum[(size_t)g * HWORDS + w] = run;
}

// Stage 2b: exclusive scan over the 8 group totals per word (in place), emit deg + block sums.
__global__ __launch_bounds__(256) void k_scanb2(unsigned* __restrict__ gsum, int* __restrict__ deg,
                                                int* __restrict__ bsum) {
    int w = blockIdx.x * 256 + threadIdx.x;
    int mysum = 0;
    if (w < HWORDS) {
        unsigned run = 0;
#pragma unroll
        for (int g = 0; g < NGRP; ++g) {
            unsigned u = gsum[(size_t)g * HWORDS + w];
            gsum[(size_t)g * HWORDS + w] = run;
            run += u;
        }
#pragma unroll
        for (int k = 0; k < 4; ++k) {
            int d = (int)((run >> (k << 3)) & 0xffu);
            deg[4 * w + k] = d;
            mysum += d;
        }
    }
    __shared__ int s[256];
    s[threadIdx.x] = mysum;
    __syncthreads();
    for (int d = 128; d > 0; d >>= 1) {
        if (threadIdx.x < d) s[threadIdx.x] += s[threadIdx.x + d];
        __syncthreads();
    }
    if (threadIdx.x == 0) bsum[blockIdx.x] = s[0];
}

// Stage 3: global offsets + invdeg; 49-block scan of bsum inlined.
__global__ __launch_bounds__(256) void k_offsets(const int* __restrict__ deg, const int* __restrict__ bsum,
                                                 int* __restrict__ offs, float* __restrict__ invdeg) {
    __shared__ int sb[64], sb0[64];
    __shared__ int s[256];
    int b = blockIdx.x, t = threadIdx.x;
    if (t < 64) {
        int v = (t < 49) ? bsum[t] : 0;
        sb[t] = v;
        sb0[t] = v;
    }
    __syncthreads();
    for (int d = 1; d < 64; d <<= 1) {
        int add = (t < 64 && t >= d) ? sb[t - d] : 0;
        __syncthreads();
        if (t < 64) sb[t] += add;
        __syncthreads();
    }
    int n0 = (b * 256 + t) * 4;
    int dl[4] = {0, 0, 0, 0};
#pragma unroll
    for (int k = 0; k < 4; ++k)
        if (n0 + k < N_NODES) dl[k] = deg[n0 + k];
    int v = dl[0] + dl[1] + dl[2] + dl[3];
    s[t] = v;
    __syncthreads();
    for (int dd = 1; dd < 256; dd <<= 1) {
        int add = (t >= dd) ? s[t - dd] : 0;
        __syncthreads();
        s[t] += add;
        __syncthreads();
    }
    int base = (sb[b] - sb0[b]) + s[t] - v;   // boff (exclusive) + intra-block exclusive
#pragma unroll
    for (int k = 0; k < 4; ++k) {
        if (n0 + k < N_NODES) {
            offs[n0 + k] = base;
            invdeg[n0 + k] = 1.0f / fmaxf((float)dl[k], 1.0f);
            base += dl[k];
        }
    }
}

// Stage 4: fill — 512 threads (8 waves/block); u8 LDS cursors; raw u16 src ids.
__global__ __launch_bounds__(512) void k_fill(const int* __restrict__ ei, const int* __restrict__ offs,
                                              const unsigned* __restrict__ hist,
                                              const unsigned* __restrict__ gpre,
                                              unsigned short* __restrict__ csr) {
    __shared__ unsigned scur[CWPP];   // 12.5 KB
    const int pass = blockIdx.x & 3;                       // 0..3 dst pass
    const int b = blockIdx.x >> 2;                         // 0..199 edge slice
    const int nbase = pass * NPP;
    const unsigned* hb = hist + (size_t)b * HWORDS + pass * CWPP;
    const unsigned* gb = gpre + (size_t)(b / SPG) * HWORDS + pass * CWPP;
    for (int i = threadIdx.x; i < CWPP; i += 512) scur[i] = hb[i] + gb[i];
    __syncthreads();
    const int e0 = b * EPB;
    for (int i = threadIdx.x; i < EPB; i += 512) {
        int d = __builtin_nontemporal_load(ei + N_EDGES + e0 + i);
        unsigned rd = (unsigned)(d - nbase);
        if (rd < (unsigned)NPP) {
            int s = ei[e0 + i];
            int sh = (rd & 3) << 3;
            unsigned old = atomicAdd(&scur[rd >> 2], 1u << sh);
            unsigned rel = (old >> sh) & 0xffu;
            csr[offs[d] + (int)rel] = (unsigned short)s;   // raw src id
        }
    }
}

// ---------------- fused layer: 16 nodes/block ----------------
// Gather: 16-deep inner stage (16 row-loads in flight per lane). Round-17 proved
// the gather is ILP-bound (8-deep beat segmented-8 by 11% with HIGHER fetch);
// mean deg 32 -> 16-deep still runs ~2 full batches per node.
__global__ __launch_bounds__(256) void k_layer16(
        const uint4* __restrict__ xq, unsigned short* __restrict__ csr,
        const int* __restrict__ offs, const int* __restrict__ deg,
        const float* __restrict__ invdeg,
        const uint4* __restrict__ wp, const float* __restrict__ bn,
        const float* __restrict__ gam, const float* __restrict__ bet,
        float* __restrict__ xout, unsigned* __restrict__ b16out,
        int write_f32, int sort_first) {
    __shared__ float H[16 * 132];              // 8448 B; A aliases the front
    __shared__ unsigned short seg[16][256];    // 8192 B (sort/gather staging, layer 0)
    __shared__ int cnt[16][4], st[16][4];      // 512 B
    uint4* A = (uint4*)H;                      // A = uint4[16*17] = 4352 B

    const int t = threadIdx.x;
    const int wv = t >> 6;
    const int lane = t & 63;
    const int slot = lane >> 4;     // node within wave
    const int m = lane & 15;        // 16B chunk within row
    const int n0 = blockIdx.x * 16; // 50000 = 16*3125 exactly
    const uint4* xm = xq + m;

    const int gi = wv * 4 + slot;
    const int node = n0 + gi;
    const int beg = offs[node];
    const int dtot = deg[node];

    float a0 = 0.f, a1 = 0.f, a2 = 0.f, a3 = 0.f, a4 = 0.f, a5 = 0.f, a6 = 0.f, a7 = 0.f;

#define GBODY8(u0, u1, u2, u3, u4, u5, u6, u7)                                    \
    a0 += ((bf_lo(u0.x) + bf_lo(u1.x)) + (bf_lo(u2.x) + bf_lo(u3.x)))             \
        + ((bf_lo(u4.x) + bf_lo(u5.x)) + (bf_lo(u6.x) + bf_lo(u7.x)));            \
    a1 += ((bf_hi(u0.x) + bf_hi(u1.x)) + (bf_hi(u2.x) + bf_hi(u3.x)))             \
        + ((bf_hi(u4.x) + bf_hi(u5.x)) + (bf_hi(u6.x) + bf_hi(u7.x)));            \
    a2 += ((bf_lo(u0.y) + bf_lo(u1.y)) + (bf_lo(u2.y) + bf_lo(u3.y)))             \
        + ((bf_lo(u4.y) + bf_lo(u5.y)) + (bf_lo(u6.y) + bf_lo(u7.y)));            \
    a3 += ((bf_hi(u0.y) + bf_hi(u1.y)) + (bf_hi(u2.y) + bf_hi(u3.y)))             \
        + ((bf_hi(u4.y) + bf_hi(u5.y)) + (bf_hi(u6.y) + bf_hi(u7.y)));            \
    a4 += ((bf_lo(u0.z) + bf_lo(u1.z)) + (bf_lo(u2.z) + bf_lo(u3.z)))             \
        + ((bf_lo(u4.z) + bf_lo(u5.z)) + (bf_lo(u6.z) + bf_lo(u7.z)));            \
    a5 += ((bf_hi(u0.z) + bf_hi(u1.z)) + (bf_hi(u2.z) + bf_hi(u3.z)))             \
        + ((bf_hi(u4.z) + bf_hi(u5.z)) + (bf_hi(u6.z) + bf_hi(u7.z)));            \
    a6 += ((bf_lo(u0.w) + bf_lo(u1.w)) + (bf_lo(u2.w) + bf_lo(u3.w)))             \
        + ((bf_lo(u4.w) + bf_lo(u5.w)) + (bf_lo(u6.w) + bf_lo(u7.w)));            \
    a7 += ((bf_hi(u0.w) + bf_hi(u1.w)) + (bf_hi(u2.w) + bf_hi(u3.w)))             \
        + ((bf_hi(u4.w) + bf_hi(u5.w)) + (bf_hi(u6.w) + bf_hi(u7.w)));

#define GBODY4(u0, u1, u2, u3)                                                    \
    a0 += (bf_lo(u0.x) + bf_lo(u1.x)) + (bf_lo(u2.x) + bf_lo(u3.x));              \
    a1 += (bf_hi(u0.x) + bf_hi(u1.x)) + (bf_hi(u2.x) + bf_hi(u3.x));              \
    a2 += (bf_lo(u0.y) + bf_lo(u1.y)) + (bf_lo(u2.y) + bf_lo(u3.y));              \
    a3 += (bf_hi(u0.y) + bf_hi(u1.y)) + (bf_hi(u2.y) + bf_hi(u3.y));              \
    a4 += (bf_lo(u0.z) + bf_lo(u1.z)) + (bf_lo(u2.z) + bf_lo(u3.z));              \
    a5 += (bf_hi(u0.z) + bf_hi(u1.z)) + (bf_hi(u2.z) + bf_hi(u3.z));              \
    a6 += (bf_lo(u0.w) + bf_lo(u1.w)) + (bf_lo(u2.w) + bf_lo(u3.w));              \
    a7 += (bf_hi(u0.w) + bf_hi(u1.w)) + (bf_hi(u2.w) + bf_hi(u3.w));

#define GBODY1(u0)                                                                \
    a0 += bf_lo(u0.x); a1 += bf_hi(u0.x);                                         \
    a2 += bf_lo(u0.y); a3 += bf_hi(u0.y);                                         \
    a4 += bf_lo(u0.z); a5 += bf_hi(u0.z);                                         \
    a6 += bf_lo(u0.w); a7 += bf_hi(u0.w);

// IDX(j): index source. Global path: csr[beg+j]. LDS path: seg[gi][j].
// 16-deep first stage: 16 independent row loads in flight per lane.
#define SEG_GATHER(IDX, JB, JE)                                                   \
    {                                                                             \
        int j = (JB);                                                             \
        const int e = (JE);                                                       \
        for (; j + 16 <= e; j += 16) {                                            \
            int s0 = IDX(j) << 4;                                                 \
            int s1 = IDX(j + 1) << 4;                                             \
            int s2 = IDX(j + 2) << 4;                                             \
            int s3 = IDX(j + 3) << 4;                                             \
            int s4 = IDX(j + 4) << 4;                                             \
            int s5 = IDX(j + 5) << 4;                                             \
            int s6 = IDX(j + 6) << 4;                                             \
            int s7 = IDX(j + 7) << 4;                                             \
            int s8 = IDX(j + 8) << 4;                                             \
            int s9 = IDX(j + 9) << 4;                                             \
            int s10 = IDX(j + 10) << 4;                                           \
            int s11 = IDX(j + 11) << 4;                                           \
            int s12 = IDX(j + 12) << 4;                                           \
            int s13 = IDX(j + 13) << 4;                                           \
            int s14 = IDX(j + 14) << 4;                                           \
            int s15 = IDX(j + 15) << 4;                                           \
            uint4 ua0 = xm[s0], ua1 = xm[s1], ua2 = xm[s2], ua3 = xm[s3];         \
            uint4 ua4 = xm[s4], ua5 = xm[s5], ua6 = xm[s6], ua7 = xm[s7];         \
            uint4 ub0 = xm[s8], ub1 = xm[s9], ub2 = xm[s10], ub3 = xm[s11];       \
            uint4 ub4 = xm[s12], ub5 = xm[s13], ub6 = xm[s14], ub7 = xm[s15];     \
            GBODY8(ua0, ua1, ua2, ua3, ua4, ua5, ua6, ua7)                        \
            GBODY8(ub0, ub1, ub2, ub3, ub4, ub5, ub6, ub7)                        \
        }                                                                         \
        for (; j + 8 <= e; j += 8) {                                              \
            int s0 = IDX(j) << 4;                                                 \
            int s1 = IDX(j + 1) << 4;                                             \
            int s2 = IDX(j + 2) << 4;                                             \
            int s3 = IDX(j + 3) << 4;                                             \
            int s4 = IDX(j + 4) << 4;                                             \
            int s5 = IDX(j + 5) << 4;                                             \
            int s6 = IDX(j + 6) << 4;                                             \
            int s7 = IDX(j + 7) << 4;                                             \
            uint4 u0 = xm[s0], u1 = xm[s1], u2 = xm[s2], u3 = xm[s3];             \
            uint4 u4 = xm[s4], u5 = xm[s5], u6 = xm[s6], u7 = xm[s7];             \
            GBODY8(u0, u1, u2, u3, u4, u5, u6, u7)                                \
        }                                                                         \
        for (; j + 4 <= e; j += 4) {                                              \
            int s0 = IDX(j) << 4;                                                 \
            int s1 = IDX(j + 1) << 4;                                             \
            int s2 = IDX(j + 2) << 4;                                             \
            int s3 = IDX(j + 3) << 4;                                             \
            uint4 u0 = xm[s0], u1 = xm[s1], u2 = xm[s2], u3 = xm[s3];             \
            GBODY4(u0, u1, u2, u3)                                                \
        }                                                                         \
        for (; j < e; ++j) {                                                      \
            uint4 u0 = xm[IDX(j) << 4];                                           \
            GBODY1(u0)                                                            \
        }                                                                         \
    }

#define IDX_G(j) ((int)csr[beg + (j)])
#define IDX_L(j) ((int)seg[gi][(j)])

    if (sort_first) {
        // ---- in-wave quarter sort (no block barriers: 16 lanes = one node, one wave) ----
        if (m < 4) cnt[gi][m] = 0;
        for (int j = m; j < dtot; j += 16) {
            unsigned short v = csr[beg + j];
            seg[gi][j] = v;
            atomicAdd(&cnt[gi][(int)v / QN], 1);
        }
        if (m == 0) {
            int c0 = cnt[gi][0], c1 = cnt[gi][1], c2 = cnt[gi][2];
            st[gi][0] = 0; st[gi][1] = c0; st[gi][2] = c0 + c1; st[gi][3] = c0 + c1 + c2;
            cnt[gi][0] = 0; cnt[gi][1] = c0; cnt[gi][2] = c0 + c1; cnt[gi][3] = c0 + c1 + c2;
        }
        unsigned val2[8];
#pragma unroll
        for (int i = 0; i < 8; ++i) {
            int j0 = m + 32 * i, j1 = j0 + 16;
            unsigned v0 = (j0 < dtot) ? (unsigned)seg[gi][j0] : 0u;
            unsigned v1 = (j1 < dtot) ? (unsigned)seg[gi][j1] : 0u;
            val2[i] = v0 | (v1 << 16);
        }
#pragma unroll
        for (int i = 0; i < 8; ++i) {
            int j0 = m + 32 * i, j1 = j0 + 16;
            if (j0 < dtot) {
                unsigned v0 = val2[i] & 0xffffu;
                int pos = atomicAdd(&cnt[gi][(int)v0 / QN], 1);
                seg[gi][pos] = (unsigned short)v0;
            }
            if (j1 < dtot) {
                unsigned v1 = val2[i] >> 16;
                int pos = atomicAdd(&cnt[gi][(int)v1 / QN], 1);
                seg[gi][pos] = (unsigned short)v1;
            }
        }
        for (int j = m; j < dtot; j += 16)      // sorted csr for layers 1-2
            csr[beg + j] = seg[gi][j];
        // gather straight from LDS, full range, full ILP
        SEG_GATHER(IDX_L, 0, dtot)
    } else {
        SEG_GATHER(IDX_G, 0, dtot)
    }

    {
        float id = invdeg[node];
        uint4 r;
        r.x = bf_pack(a0 * id, a1 * id);
        r.y = bf_pack(a2 * id, a3 * id);
        r.z = bf_pack(a4 * id, a5 * id);
        r.w = bf_pack(a6 * id, a7 * id);
        A[gi * 17 + m] = r;
    }
    __syncthreads();

    // ---- phase 2: MFMA GEMM — 16 rows x 128 cols, K=256; wave w owns cols w*32..+31 ----
    const int quad = lane >> 4;
    const int nl = lane & 15;
    const int nb = wv * 32;
    floatx4 acc0 = {0.f, 0.f, 0.f, 0.f}, acc1 = acc0;
#pragma unroll
    for (int kb = 0; kb < 8; ++kb) {
        uint4 av = (kb < 4) ? A[nl * 17 + kb * 4 + quad]
                            : xq[(n0 + nl) * 16 + (kb - 4) * 4 + quad];
        uint4 b0 = wp[(kb * 128 + nb + nl) * 4 + quad];
        uint4 b1 = wp[(kb * 128 + nb + 16 + nl) * 4 + quad];
        short8 as = *(short8*)&av;
        short8 b0s = *(short8*)&b0, b1s = *(short8*)&b1;
        acc0 = __builtin_amdgcn_mfma_f32_16x16x32_bf16(as, b0s, acc0, 0, 0, 0);
        acc1 = __builtin_amdgcn_mfma_f32_16x16x32_bf16(as, b1s, acc1, 0, 0, 0);
    }
    __syncthreads();   // A (aliased by H) fully read by all waves

    // ---- phase 3: bias -> H ----
    float bn0 = bn[nb + nl];
    float bn1 = bn[nb + 16 + nl];
#pragma unroll
    for (int reg = 0; reg < 4; ++reg) {
        int rr = quad * 4 + reg;
        H[rr * 132 + nb + nl] = acc0[reg] + bn0;
        H[rr * 132 + nb + 16 + nl] = acc1[reg] + bn1;
    }
    __syncthreads();

    // ---- phase 4: LayerNorm + ReLU + store (16 threads/row, 8 cols each) ----
    const int row = t >> 4;    // 0..15
    const int sub = t & 15;
    const float* hr = &H[row * 132 + sub * 8];
    float v[8];
    float s = 0.f, s2 = 0.f;
#pragma unroll
    for (int i = 0; i < 8; i++) {
        v[i] = hr[i];
        s += v[i];
        s2 += v[i] * v[i];
    }
#pragma unroll
    for (int msk = 1; msk < 16; msk <<= 1) {
        s += __shfl_xor(s, msk);
        s2 += __shfl_xor(s2, msk);
    }
    float mean = s * (1.f / 128.f);
    float var = s2 * (1.f / 128.f) - mean * mean;
    float rstd = rsqrtf(var + 1e-5f);
    const int gr = n0 + row;
    const int cb = sub * 8;
    float o[8];
#pragma unroll
    for (int i = 0; i < 8; i++)
        o[i] = fmaxf((v[i] - mean) * rstd * gam[cb + i] + bet[cb + i], 0.f);
    if (write_f32) {
        *(float4*)&xout[(size_t)gr * HID + cb] = *(float4*)&o[0];
        *(float4*)&xout[(size_t)gr * HID + cb + 4] = *(float4*)&o[4];
    }
    unsigned p[4];
#pragma unroll
    for (int i = 0; i < 4; i++) p[i] = bf_pack(o[2 * i], o[2 * i + 1]);
    *(uint4*)&b16out[(size_t)gr * 64 + (cb >> 1)] = *(uint4*)&p[0];
}

// ---------------- graph mean-pool: 4 blocks/graph -> partials, then combine ----------------

__global__ __launch_bounds__(1024) void k_pool1(const unsigned* __restrict__ xb,
                                                const int* __restrict__ batch,
                                                float* __restrict__ partial, int* __restrict__ cnt) {
    const int bid = blockIdx.x;        // 0..255
    const int g = bid >> 2;
    const int part = bid & 3;
    __shared__ int s_beg, s_end;
    if (threadIdx.x == 0) {
        int lo = 0, hi = N_NODES;
        while (lo < hi) { int mid = (lo + hi) >> 1; if (batch[mid] < g) lo = mid + 1; else hi = mid; }
        s_beg = lo;
        lo = 0; hi = N_NODES;
        while (lo < hi) { int mid = (lo + hi) >> 1; if (batch[mid] < g + 1) lo = mid + 1; else hi = mid; }
        s_end = lo;
    }
    __syncthreads();
    const int beg = s_beg, end = s_end;
    const int w = threadIdx.x & 63;    // u32 word (2 cols)
    const int q = threadIdx.x >> 6;    // row group 0..15
    float ax = 0.f, ay = 0.f;
    for (int r = beg + part * 16 + q; r < end; r += 64) {
        unsigned u = __builtin_nontemporal_load(xb + (size_t)r * 64 + w);
        ax += bf_lo(u);
        ay += bf_hi(u);
    }
    __shared__ float sx[16][64], sy[16][64];
    sx[q][w] = ax;
    sy[q][w] = ay;
    __syncthreads();
    if (q == 0) {
        float tx = 0.f, ty = 0.f;
#pragma unroll
        for (int i = 0; i < 16; i++) { tx += sx[i][w]; ty += sy[i][w]; }
        float2 r;
        r.x = tx;
        r.y = ty;
        *(float2*)&partial[(size_t)bid * 128 + w * 2] = r;
    }
    if (part == 0 && threadIdx.x == 0) cnt[g] = end - beg;
}

__global__ __launch_bounds__(256) void k_pool2(const float* __restrict__ partial,
                                               const int* __restrict__ cnt,
                                               float* __restrict__ out) {
    int idx = blockIdx.x * 256 + threadIdx.x;   // 8192 = 64 graphs x 128 cols
    int g = idx >> 7;
    float s = partial[(size_t)(g * 4 + 0) * 128 + (idx & 127)]
            + partial[(size_t)(g * 4 + 1) * 128 + (idx & 127)]
            + partial[(size_t)(g * 4 + 2) * 128 + (idx & 127)]
            + partial[(size_t)(g * 4 + 3) * 128 + (idx & 127)];
    out[idx] = s / fmaxf((float)cnt[g], 1.f);
}

extern "C" void kernel_launch(void* const* d_in, const int* in_sizes, int n_in,
                              void* d_out, int out_size, void* d_ws, size_t ws_size,
                              hipStream_t stream) {
    const float* x0 = (const float*)d_in[0];
    const float* Wn = (const float*)d_in[1];
    const float* bn = (const float*)d_in[2];
    const float* Wr = (const float*)d_in[3];
    const float* gam = (const float*)d_in[4];
    const float* bet = (const float*)d_in[5];
    const int* ei = (const int*)d_in[6];
    const int* batch = (const int*)d_in[7];

    float* out = (float*)d_out;                 // [0,8192): graph_emb ; [8192,...): node_emb
    float* node_out = out + N_GRAPHS * HID;

    unsigned* ws = (unsigned*)d_ws;
    int* deg = (int*)(ws + WS_DEG);
    int* bsum = (int*)(ws + WS_BSUM);
    int* offs = (int*)(ws + WS_OFFS);
    float* invdeg = (float*)(ws + WS_INVD);
    unsigned short* csr = (unsigned short*)(ws + WS_CSR);
    unsigned* hist = ws + WS_XB_B;    // hist during build; x buffer B after
    unsigned* gsum = ws + WS_GSUM;    // scan-group totals (build only)
    unsigned* xa = ws + WS_XB_A;      // x buffer A
    unsigned* xbb = ws + WS_XB_B;
    uint4* wp = (uint4*)(ws + WS_WP);
    // pool scratch reuses the (dead-after-layers) csr region
    float* partial = (float*)(ws + WS_CSR);
    int* cnt = (int*)(ws + WS_CSR + 256 * 128);

    k_prephist<<<1775, 1024, 0, stream>>>((const float4*)x0, (uint2*)xa, Wn, Wr, wp, ei, hist);
    k_scanb1<<<NGRP * 49, 256, 0, stream>>>(hist, gsum);
    k_scanb2<<<49, 256, 0, stream>>>(gsum, deg, bsum);
    k_offsets<<<49, 256, 0, stream>>>(deg, bsum, offs, invdeg);
    k_fill<<<HB * 4, 512, 0, stream>>>(ei, offs, hist, gsum, csr);

    const int lb = N_NODES / 16;                   // 3125 blocks

    // ping-pong: l0 A->B, l1 B->A, l2 A->B; layer 0 also quarter-sorts csr (in-wave)
    for (int l = 0; l < 3; ++l) {
        const unsigned* xin = (l & 1) ? xbb : xa;
        unsigned* xout16 = (l & 1) ? xa : xbb;
        k_layer16<<<lb, 256, 0, stream>>>((const uint4*)xin, csr, offs, deg, invdeg,
                                          wp + (size_t)l * 4096, bn + (size_t)l * HID,
                                          gam + (size_t)l * HID, bet + (size_t)l * HID,
                                          node_out, xout16, l == 2 ? 1 : 0, l == 0 ? 1 : 0);
    }

    k_pool1<<<N_GRAPHS * 4, 1024, 0, stream>>>(xbb, batch, partial, cnt);
    k_pool2<<<32, 256, 0, stream>>>(partial, cnt, out);
}

// Round 20
// 384.954 us; speedup vs baseline: 1.0526x; 1.0526x over previous
//
#include <hip/hip_runtime.h>

#define N_NODES 50000
#define N_EDGES 1600000
#define HID     128
#define N_GRAPHS 64

#define HB 200                            // hist slices (edge-position based)
#define EPB (N_EDGES / HB)                // 8000 edges per slice
#define HWORDS 12500                      // 50000 nodes packed u8 x4 per word
#define NGRP 8                            // slice groups for 2-level scan
#define SPG (HB / NGRP)                   // 25 slices per group
#define NQ 4                              // src quarters (sort windows, 3.2MB < 4MB L2)
#define QN (N_NODES / NQ)                 // 12500 srcs per quarter
#define NPPF 25000                        // dst nodes per fill pass (2 passes)
#define CWPF (NPPF / 4)                   // 6250 cursor words per fill pass

// workspace layout (4-byte words) — WS_END identical to the verified baseline.
#define WS_DEG   0u         // int[50000]
#define WS_BSUM  50000u     // int[256]
#define WS_BOFF  50256u     // int[256] (unused, layout stability)
#define WS_OFFS  50512u     // int[50000]
#define WS_INVD  100512u    // float[50000]
#define WS_CSR   150512u    // u16[1600000] (800K words); pool partials here after layers
#define WS_QOFF  950512u    // (unused; kept for layout stability)
#define WS_XB_B  1750512u   // uint[3200000]: hist(2.5M)+gsum during build; x ping B after
#define WS_GSUM  (WS_XB_B + 2500000u)     // uint[100000] scan-group totals (build only)
#define WS_XB_A  4950512u   // uint[3200000]: x ping buffer A (bf16 x2: 50000x128)
#define WS_WP    8150512u   // uint[49152] = packed W frags: 3 layers x 4096 uint4
#define WS_END   8199664u

typedef __attribute__((ext_vector_type(8))) short short8;
typedef __attribute__((ext_vector_type(4))) float floatx4;

// ---- bf16 helpers (raw, RN-even pack; fp32 math everywhere) ----
__device__ __forceinline__ float bf_lo(unsigned u) { return __uint_as_float(u << 16); }
__device__ __forceinline__ float bf_hi(unsigned u) { return __uint_as_float(u & 0xffff0000u); }
__device__ __forceinline__ unsigned bf_rn(float f) {
    unsigned u = __float_as_uint(f);
    unsigned r = ((u >> 16) & 1u) + 0x7fffu;
    return (u + r) >> 16;
}
__device__ __forceinline__ unsigned bf_pack(float lo, float hi) {
    return bf_rn(lo) | (bf_rn(hi) << 16);
}

// ---------------- prep+hist fused, 1024 threads ----------------
__global__ __launch_bounds__(1024) void k_prephist(const float4* __restrict__ x, uint2* __restrict__ o,
                                                   const float* __restrict__ Wn, const float* __restrict__ Wr,
                                                   uint4* __restrict__ wp, const int* __restrict__ ei,
                                                   unsigned* __restrict__ hist) {
    __shared__ unsigned sh[HWORDS];   // 50 KB (hist branch)
    if (blockIdx.x < 1563) {
        int i = blockIdx.x * 1024 + threadIdx.x;     // 1.6M float4 total
        if (i < 1600000) {
            float4 v = x[i];
            uint2 r;
            r.x = bf_pack(v.x, v.y);
            r.y = bf_pack(v.z, v.w);
            o[i] = r;
        }
    } else if (blockIdx.x < 1575) {
        int idx = (blockIdx.x - 1563) * 1024 + threadIdx.x;   // 12288 total
        int layer = idx >> 12;
        int rem = idx & 4095;
        int kb = rem >> 9;
        int n = (rem >> 2) & 127;
        int quad = rem & 3;
        float v[8];
#pragma unroll
        for (int j = 0; j < 8; j++) {
            int k = kb * 32 + quad * 8 + j;
            v[j] = (k < 128) ? Wn[layer * 16384 + k * 128 + n]
                             : Wr[layer * 16384 + (k - 128) * 128 + n];
        }
        uint4 r;
        r.x = bf_pack(v[0], v[1]);
        r.y = bf_pack(v[2], v[3]);
        r.z = bf_pack(v[4], v[5]);
        r.w = bf_pack(v[6], v[7]);
        wp[idx] = r;
    } else {
        const int hb = blockIdx.x - 1575;            // 0..199 hist slice
        for (int i = threadIdx.x; i < HWORDS; i += 1024) sh[i] = 0;
        __syncthreads();
        const int e0 = hb * EPB;
        for (int i = threadIdx.x; i < EPB; i += 1024) {
            int d = __builtin_nontemporal_load(ei + N_EDGES + e0 + i);
            atomicAdd(&sh[d >> 2], 1u << ((d & 3) << 3));
        }
        __syncthreads();
        unsigned* hp = hist + (size_t)hb * HWORDS;
        for (int i = threadIdx.x; i < HWORDS; i += 1024) hp[i] = sh[i];
    }
}

// ---------------- CSR build ----------------

// Stage 2a: group-local exclusive scan over 25 slices (in place) + per-group totals.
__global__ __launch_bounds__(256) void k_scanb1(unsigned* __restrict__ hist, unsigned* __restrict__ gsum) {
    int wb = blockIdx.x % 49;
    int g = blockIdx.x / 49;
    int w = wb * 256 + threadIdx.x;
    if (w >= HWORDS) return;
    size_t base = (size_t)(g * SPG) * HWORDS + w;
    unsigned run = 0;
#pragma unroll 5
    for (int b = 0; b < SPG; ++b) {
        unsigned u = hist[base + (size_t)b * HWORDS];
        hist[base + (size_t)b * HWORDS] = run;
        run += u;
    }
    gsum[(size_t)g * HWORDS + w] = run;
}

// Stage 2b: exclusive scan over the 8 group totals per word (in place), emit deg + block sums.
__global__ __launch_bounds__(256) void k_scanb2(unsigned* __restrict__ gsum, int* __restrict__ deg,
                                                int* __restrict__ bsum) {
    int w = blockIdx.x * 256 + threadIdx.x;
    int mysum = 0;
    if (w < HWORDS) {
        unsigned run = 0;
#pragma unroll
        for (int g = 0; g < NGRP; ++g) {
            unsigned u = gsum[(size_t)g * HWORDS + w];
            gsum[(size_t)g * HWORDS + w] = run;
            run += u;
        }
#pragma unroll
        for (int k = 0; k < 4; ++k) {
            int d = (int)((run >> (k << 3)) & 0xffu);
            deg[4 * w + k] = d;
            mysum += d;
        }
    }
    __shared__ int s[256];
    s[threadIdx.x] = mysum;
    __syncthreads();
    for (int d = 128; d > 0; d >>= 1) {
        if (threadIdx.x < d) s[threadIdx.x] += s[threadIdx.x + d];
        __syncthreads();
    }
    if (threadIdx.x == 0) bsum[blockIdx.x] = s[0];
}

// Stage 3: global offsets + invdeg; 49-block scan of bsum inlined.
__global__ __launch_bounds__(256) void k_offsets(const int* __restrict__ deg, const int* __restrict__ bsum,
                                                 int* __restrict__ offs, float* __restrict__ invdeg) {
    __shared__ int sb[64], sb0[64];
    __shared__ int s[256];
    int b = blockIdx.x, t = threadIdx.x;
    if (t < 64) {
        int v = (t < 49) ? bsum[t] : 0;
        sb[t] = v;
        sb0[t] = v;
    }
    __syncthreads();
    for (int d = 1; d < 64; d <<= 1) {
        int add = (t < 64 && t >= d) ? sb[t - d] : 0;
        __syncthreads();
        if (t < 64) sb[t] += add;
        __syncthreads();
    }
    int n0 = (b * 256 + t) * 4;
    int dl[4] = {0, 0, 0, 0};
#pragma unroll
    for (int k = 0; k < 4; ++k)
        if (n0 + k < N_NODES) dl[k] = deg[n0 + k];
    int v = dl[0] + dl[1] + dl[2] + dl[3];
    s[t] = v;
    __syncthreads();
    for (int dd = 1; dd < 256; dd <<= 1) {
        int add = (t >= dd) ? s[t - dd] : 0;
        __syncthreads();
        s[t] += add;
        __syncthreads();
    }
    int base = (sb[b] - sb0[b]) + s[t] - v;   // boff (exclusive) + intra-block exclusive
#pragma unroll
    for (int k = 0; k < 4; ++k) {
        if (n0 + k < N_NODES) {
            offs[n0 + k] = base;
            invdeg[n0 + k] = 1.0f / fmaxf((float)dl[k], 1.0f);
            base += dl[k];
        }
    }
}

// Stage 4: fill — 200 slices x 2 dst passes = 400 blocks, 1024 threads (16 waves);
// halves the 4x edge-array re-read of the 4-pass version. u8 LDS cursors; u16 src ids.
__global__ __launch_bounds__(1024) void k_fill(const int* __restrict__ ei, const int* __restrict__ offs,
                                               const unsigned* __restrict__ hist,
                                               const unsigned* __restrict__ gpre,
                                               unsigned short* __restrict__ csr) {
    __shared__ unsigned scur[CWPF];   // 25 KB
    const int pass = blockIdx.x & 1;                       // 0..1 dst pass
    const int b = blockIdx.x >> 1;                         // 0..199 edge slice
    const int nbase = pass * NPPF;
    const unsigned* hb = hist + (size_t)b * HWORDS + pass * CWPF;
    const unsigned* gb = gpre + (size_t)(b / SPG) * HWORDS + pass * CWPF;
    for (int i = threadIdx.x; i < CWPF; i += 1024) scur[i] = hb[i] + gb[i];
    __syncthreads();
    const int e0 = b * EPB;
    for (int i = threadIdx.x; i < EPB; i += 1024) {
        int d = __builtin_nontemporal_load(ei + N_EDGES + e0 + i);
        unsigned rd = (unsigned)(d - nbase);
        if (rd < (unsigned)NPPF) {
            int s = ei[e0 + i];
            int sh = (rd & 3) << 3;
            unsigned old = atomicAdd(&scur[rd >> 2], 1u << sh);
            unsigned rel = (old >> sh) & 0xffu;
            csr[offs[d] + (int)rel] = (unsigned short)s;   // raw src id
        }
    }
}

// ---------------- fused layer: 16 nodes/block ----------------
// 8-deep gather (verified r17 sweet spot: 52 VGPR / 8 waves/SIMD; 16-deep cost
// occupancy 36->30% and regressed). Quarter locality lives in csr's sorted order.
__global__ __launch_bounds__(256) void k_layer16(
        const uint4* __restrict__ xq, unsigned short* __restrict__ csr,
        const int* __restrict__ offs, const int* __restrict__ deg,
        const float* __restrict__ invdeg,
        const uint4* __restrict__ wp, const float* __restrict__ bn,
        const float* __restrict__ gam, const float* __restrict__ bet,
        float* __restrict__ xout, unsigned* __restrict__ b16out,
        int write_f32, int sort_first) {
    __shared__ float H[16 * 132];              // 8448 B; A aliases the front
    __shared__ unsigned short seg[16][256];    // 8192 B (sort/gather staging, layer 0)
    __shared__ int cnt[16][4], st[16][4];      // 512 B
    uint4* A = (uint4*)H;                      // A = uint4[16*17] = 4352 B

    const int t = threadIdx.x;
    const int wv = t >> 6;
    const int lane = t & 63;
    const int slot = lane >> 4;     // node within wave
    const int m = lane & 15;        // 16B chunk within row
    const int n0 = blockIdx.x * 16; // 50000 = 16*3125 exactly
    const uint4* xm = xq + m;

    const int gi = wv * 4 + slot;
    const int node = n0 + gi;
    const int beg = offs[node];
    const int dtot = deg[node];

    float a0 = 0.f, a1 = 0.f, a2 = 0.f, a3 = 0.f, a4 = 0.f, a5 = 0.f, a6 = 0.f, a7 = 0.f;

#define GBODY8(u0, u1, u2, u3, u4, u5, u6, u7)                                    \
    a0 += ((bf_lo(u0.x) + bf_lo(u1.x)) + (bf_lo(u2.x) + bf_lo(u3.x)))             \
        + ((bf_lo(u4.x) + bf_lo(u5.x)) + (bf_lo(u6.x) + bf_lo(u7.x)));            \
    a1 += ((bf_hi(u0.x) + bf_hi(u1.x)) + (bf_hi(u2.x) + bf_hi(u3.x)))             \
        + ((bf_hi(u4.x) + bf_hi(u5.x)) + (bf_hi(u6.x) + bf_hi(u7.x)));            \
    a2 += ((bf_lo(u0.y) + bf_lo(u1.y)) + (bf_lo(u2.y) + bf_lo(u3.y)))             \
        + ((bf_lo(u4.y) + bf_lo(u5.y)) + (bf_lo(u6.y) + bf_lo(u7.y)));            \
    a3 += ((bf_hi(u0.y) + bf_hi(u1.y)) + (bf_hi(u2.y) + bf_hi(u3.y)))             \
        + ((bf_hi(u4.y) + bf_hi(u5.y)) + (bf_hi(u6.y) + bf_hi(u7.y)));            \
    a4 += ((bf_lo(u0.z) + bf_lo(u1.z)) + (bf_lo(u2.z) + bf_lo(u3.z)))             \
        + ((bf_lo(u4.z) + bf_lo(u5.z)) + (bf_lo(u6.z) + bf_lo(u7.z)));            \
    a5 += ((bf_hi(u0.z) + bf_hi(u1.z)) + (bf_hi(u2.z) + bf_hi(u3.z)))             \
        + ((bf_hi(u4.z) + bf_hi(u5.z)) + (bf_hi(u6.z) + bf_hi(u7.z)));            \
    a6 += ((bf_lo(u0.w) + bf_lo(u1.w)) + (bf_lo(u2.w) + bf_lo(u3.w)))             \
        + ((bf_lo(u4.w) + bf_lo(u5.w)) + (bf_lo(u6.w) + bf_lo(u7.w)));            \
    a7 += ((bf_hi(u0.w) + bf_hi(u1.w)) + (bf_hi(u2.w) + bf_hi(u3.w)))             \
        + ((bf_hi(u4.w) + bf_hi(u5.w)) + (bf_hi(u6.w) + bf_hi(u7.w)));

#define GBODY4(u0, u1, u2, u3)                                                    \
    a0 += (bf_lo(u0.x) + bf_lo(u1.x)) + (bf_lo(u2.x) + bf_lo(u3.x));              \
    a1 += (bf_hi(u0.x) + bf_hi(u1.x)) + (bf_hi(u2.x) + bf_hi(u3.x));              \
    a2 += (bf_lo(u0.y) + bf_lo(u1.y)) + (bf_lo(u2.y) + bf_lo(u3.y));              \
    a3 += (bf_hi(u0.y) + bf_hi(u1.y)) + (bf_hi(u2.y) + bf_hi(u3.y));              \
    a4 += (bf_lo(u0.z) + bf_lo(u1.z)) + (bf_lo(u2.z) + bf_lo(u3.z));              \
    a5 += (bf_hi(u0.z) + bf_hi(u1.z)) + (bf_hi(u2.z) + bf_hi(u3.z));              \
    a6 += (bf_lo(u0.w) + bf_lo(u1.w)) + (bf_lo(u2.w) + bf_lo(u3.w));              \
    a7 += (bf_hi(u0.w) + bf_hi(u1.w)) + (bf_hi(u2.w) + bf_hi(u3.w));

#define GBODY1(u0)                                                                \
    a0 += bf_lo(u0.x); a1 += bf_hi(u0.x);                                         \
    a2 += bf_lo(u0.y); a3 += bf_hi(u0.y);                                         \
    a4 += bf_lo(u0.z); a5 += bf_hi(u0.z);                                         \
    a6 += bf_lo(u0.w); a7 += bf_hi(u0.w);

// IDX(j): index source. Global path: csr[beg+j]. LDS path: seg[gi][j].
#define SEG_GATHER(IDX, JB, JE)                                                   \
    {                                                                             \
        int j = (JB);                                                             \
        const int e = (JE);                                                       \
        for (; j + 8 <= e; j += 8) {                                              \
            int s0 = IDX(j) << 4;                                                 \
            int s1 = IDX(j + 1) << 4;                                             \
            int s2 = IDX(j + 2) << 4;                                             \
            int s3 = IDX(j + 3) << 4;                                             \
            int s4 = IDX(j + 4) << 4;                                             \
            int s5 = IDX(j + 5) << 4;                                             \
            int s6 = IDX(j + 6) << 4;                                             \
            int s7 = IDX(j + 7) << 4;                                             \
            uint4 u0 = xm[s0], u1 = xm[s1], u2 = xm[s2], u3 = xm[s3];             \
            uint4 u4 = xm[s4], u5 = xm[s5], u6 = xm[s6], u7 = xm[s7];             \
            GBODY8(u0, u1, u2, u3, u4, u5, u6, u7)                                \
        }                                                                         \
        for (; j + 4 <= e; j += 4) {                                              \
            int s0 = IDX(j) << 4;                                                 \
            int s1 = IDX(j + 1) << 4;                                             \
            int s2 = IDX(j + 2) << 4;                                             \
            int s3 = IDX(j + 3) << 4;                                             \
            uint4 u0 = xm[s0], u1 = xm[s1], u2 = xm[s2], u3 = xm[s3];             \
            GBODY4(u0, u1, u2, u3)                                                \
        }                                                                         \
        for (; j < e; ++j) {                                                      \
            uint4 u0 = xm[IDX(j) << 4];                                           \
            GBODY1(u0)                                                            \
        }                                                                         \
    }

#define IDX_G(j) ((int)csr[beg + (j)])
#define IDX_L(j) ((int)seg[gi][(j)])

    if (sort_first) {
        // ---- in-wave quarter sort (no block barriers: 16 lanes = one node, one wave) ----
        if (m < 4) cnt[gi][m] = 0;
        for (int j = m; j < dtot; j += 16) {
            unsigned short v = csr[beg + j];
            seg[gi][j] = v;
            atomicAdd(&cnt[gi][(int)v / QN], 1);
        }
        if (m == 0) {
            int c0 = cnt[gi][0], c1 = cnt[gi][1], c2 = cnt[gi][2];
            st[gi][0] = 0; st[gi][1] = c0; st[gi][2] = c0 + c1; st[gi][3] = c0 + c1 + c2;
            cnt[gi][0] = 0; cnt[gi][1] = c0; cnt[gi][2] = c0 + c1; cnt[gi][3] = c0 + c1 + c2;
        }
        unsigned val2[8];
#pragma unroll
        for (int i = 0; i < 8; ++i) {
            int j0 = m + 32 * i, j1 = j0 + 16;
            unsigned v0 = (j0 < dtot) ? (unsigned)seg[gi][j0] : 0u;
            unsigned v1 = (j1 < dtot) ? (unsigned)seg[gi][j1] : 0u;
            val2[i] = v0 | (v1 << 16);
        }
#pragma unroll
        for (int i = 0; i < 8; ++i) {
            int j0 = m + 32 * i, j1 = j0 + 16;
            if (j0 < dtot) {
                unsigned v0 = val2[i] & 0xffffu;
                int pos = atomicAdd(&cnt[gi][(int)v0 / QN], 1);
                seg[gi][pos] = (unsigned short)v0;
            }
            if (j1 < dtot) {
                unsigned v1 = val2[i] >> 16;
                int pos = atomicAdd(&cnt[gi][(int)v1 / QN], 1);
                seg[gi][pos] = (unsigned short)v1;
            }
        }
        for (int j = m; j < dtot; j += 16)      // sorted csr for layers 1-2
            csr[beg + j] = seg[gi][j];
        // gather straight from LDS, full range, full 8-deep ILP
        SEG_GATHER(IDX_L, 0, dtot)
    } else {
        SEG_GATHER(IDX_G, 0, dtot)
    }

    {
        float id = invdeg[node];
        uint4 r;
        r.x = bf_pack(a0 * id, a1 * id);
        r.y = bf_pack(a2 * id, a3 * id);
        r.z = bf_pack(a4 * id, a5 * id);
        r.w = bf_pack(a6 * id, a7 * id);
        A[gi * 17 + m] = r;
    }
    __syncthreads();

    // ---- phase 2: MFMA GEMM — 16 rows x 128 cols, K=256; wave w owns cols w*32..+31 ----
    const int quad = lane >> 4;
    const int nl = lane & 15;
    const int nb = wv * 32;
    floatx4 acc0 = {0.f, 0.f, 0.f, 0.f}, acc1 = acc0;
#pragma unroll
    for (int kb = 0; kb < 8; ++kb) {
        uint4 av = (kb < 4) ? A[nl * 17 + kb * 4 + quad]
                            : xq[(n0 + nl) * 16 + (kb - 4) * 4 + quad];
        uint4 b0 = wp[(kb * 128 + nb + nl) * 4 + quad];
        uint4 b1 = wp[(kb * 128 + nb + 16 + nl) * 4 + quad];
        short8 as = *(short8*)&av;
        short8 b0s = *(short8*)&b0, b1s = *(short8*)&b1;
        acc0 = __builtin_amdgcn_mfma_f32_16x16x32_bf16(as, b0s, acc0, 0, 0, 0);
        acc1 = __builtin_amdgcn_mfma_f32_16x16x32_bf16(as, b1s, acc1, 0, 0, 0);
    }
    __syncthreads();   // A (aliased by H) fully read by all waves

    // ---- phase 3: bias -> H ----
    float bn0 = bn[nb + nl];
    float bn1 = bn[nb + 16 + nl];
#pragma unroll
    for (int reg = 0; reg < 4; ++reg) {
        int rr = quad * 4 + reg;
        H[rr * 132 + nb + nl] = acc0[reg] + bn0;
        H[rr * 132 + nb + 16 + nl] = acc1[reg] + bn1;
    }
    __syncthreads();

    // ---- phase 4: LayerNorm + ReLU + store (16 threads/row, 8 cols each) ----
    const int row = t >> 4;    // 0..15
    const int sub = t & 15;
    const float* hr = &H[row * 132 + sub * 8];
    float v[8];
    float s = 0.f, s2 = 0.f;
#pragma unroll
    for (int i = 0; i < 8; i++) {
        v[i] = hr[i];
        s += v[i];
        s2 += v[i] * v[i];
    }
#pragma unroll
    for (int msk = 1; msk < 16; msk <<= 1) {
        s += __shfl_xor(s, msk);
        s2 += __shfl_xor(s2, msk);
    }
    float mean = s * (1.f / 128.f);
    float var = s2 * (1.f / 128.f) - mean * mean;
    float rstd = rsqrtf(var + 1e-5f);
    const int gr = n0 + row;
    const int cb = sub * 8;
    float o[8];
#pragma unroll
    for (int i = 0; i < 8; i++)
        o[i] = fmaxf((v[i] - mean) * rstd * gam[cb + i] + bet[cb + i], 0.f);
    if (write_f32) {
        *(float4*)&xout[(size_t)gr * HID + cb] = *(float4*)&o[0];
        *(float4*)&xout[(size_t)gr * HID + cb + 4] = *(float4*)&o[4];
    }
    unsigned p[4];
#pragma unroll
    for (int i = 0; i < 4; i++) p[i] = bf_pack(o[2 * i], o[2 * i + 1]);
    *(uint4*)&b16out[(size_t)gr * 64 + (cb >> 1)] = *(uint4*)&p[0];
}

// ---------------- graph mean-pool: 4 blocks/graph -> partials, then combine ----------------

__global__ __launch_bounds__(1024) void k_pool1(const unsigned* __restrict__ xb,
                                                const int* __restrict__ batch,
                                                float* __restrict__ partial, int* __restrict__ cnt) {
    const int bid = blockIdx.x;        // 0..255
    const int g = bid >> 2;
    const int part = bid & 3;
    __shared__ int s_beg, s_end;
    if (threadIdx.x == 0) {
        int lo = 0, hi = N_NODES;
        while (lo < hi) { int mid = (lo + hi) >> 1; if (batch[mid] < g) lo = mid + 1; else hi = mid; }
        s_beg = lo;
        lo = 0; hi = N_NODES;
        while (lo < hi) { int mid = (lo + hi) >> 1; if (batch[mid] < g + 1) lo = mid + 1; else hi = mid; }
        s_end = lo;
    }
    __syncthreads();
    const int beg = s_beg, end = s_end;
    const int w = threadIdx.x & 63;    // u32 word (2 cols)
    const int q = threadIdx.x >> 6;    // row group 0..15
    float ax = 0.f, ay = 0.f;
    for (int r = beg + part * 16 + q; r < end; r += 64) {
        unsigned u = __builtin_nontemporal_load(xb + (size_t)r * 64 + w);
        ax += bf_lo(u);
        ay += bf_hi(u);
    }
    __shared__ float sx[16][64], sy[16][64];
    sx[q][w] = ax;
    sy[q][w] = ay;
    __syncthreads();
    if (q == 0) {
        float tx = 0.f, ty = 0.f;
#pragma unroll
        for (int i = 0; i < 16; i++) { tx += sx[i][w]; ty += sy[i][w]; }
        float2 r;
        r.x = tx;
        r.y = ty;
        *(float2*)&partial[(size_t)bid * 128 + w * 2] = r;
    }
    if (part == 0 && threadIdx.x == 0) cnt[g] = end - beg;
}

__global__ __launch_bounds__(256) void k_pool2(const float* __restrict__ partial,
                                               const int* __restrict__ cnt,
                                               float* __restrict__ out) {
    int idx = blockIdx.x * 256 + threadIdx.x;   // 8192 = 64 graphs x 128 cols
    int g = idx >> 7;
    float s = partial[(size_t)(g * 4 + 0) * 128 + (idx & 127)]
            + partial[(size_t)(g * 4 + 1) * 128 + (idx & 127)]
            + partial[(size_t)(g * 4 + 2) * 128 + (idx & 127)]
            + partial[(size_t)(g * 4 + 3) * 128 + (idx & 127)];
    out[idx] = s / fmaxf((float)cnt[g], 1.f);
}

extern "C" void kernel_launch(void* const* d_in, const int* in_sizes, int n_in,
                              void* d_out, int out_size, void* d_ws, size_t ws_size,
                              hipStream_t stream) {
    const float* x0 = (const float*)d_in[0];
    const float* Wn = (const float*)d_in[1];
    const float* bn = (const float*)d_in[2];
    const float* Wr = (const float*)d_in[3];
    const float* gam = (const float*)d_in[4];
    const float* bet = (const float*)d_in[5];
    const int* ei = (const int*)d_in[6];
    const int* batch = (const int*)d_in[7];

    float* out = (float*)d_out;                 // [0,8192): graph_emb ; [8192,...): node_emb
    float* node_out = out + N_GRAPHS * HID;

    unsigned* ws = (unsigned*)d_ws;
    int* deg = (int*)(ws + WS_DEG);
    int* bsum = (int*)(ws + WS_BSUM);
    int* offs = (int*)(ws + WS_OFFS);
    float* invdeg = (float*)(ws + WS_INVD);
    unsigned short* csr = (unsigned short*)(ws + WS_CSR);
    unsigned* hist = ws + WS_XB_B;    // hist during build; x buffer B after
    unsigned* gsum = ws + WS_GSUM;    // scan-group totals (build only)
    unsigned* xa = ws + WS_XB_A;      // x buffer A
    unsigned* xbb = ws + WS_XB_B;
    uint4* wp = (uint4*)(ws + WS_WP);
    // pool scratch reuses the (dead-after-layers) csr region
    float* partial = (float*)(ws + WS_CSR);
    int* cnt = (int*)(ws + WS_CSR + 256 * 128);

    k_prephist<<<1775, 1024, 0, stream>>>((const float4*)x0, (uint2*)xa, Wn, Wr, wp, ei, hist);
    k_scanb1<<<NGRP * 49, 256, 0, stream>>>(hist, gsum);
    k_scanb2<<<49, 256, 0, stream>>>(gsum, deg, bsum);
    k_offsets<<<49, 256, 0, stream>>>(deg, bsum, offs, invdeg);
    k_fill<<<HB * 2, 1024, 0, stream>>>(ei, offs, hist, gsum, csr);

    const int lb = N_NODES / 16;                   // 3125 blocks

    // ping-pong: l0 A->B, l1 B->A, l2 A->B; layer 0 also quarter-sorts csr (in-wave)
    for (int l = 0; l < 3; ++l) {
        const unsigned* xin = (l & 1) ? xbb : xa;
        unsigned* xout16 = (l & 1) ? xa : xbb;
        k_layer16<<<lb, 256, 0, stream>>>((const uint4*)xin, csr, offs, deg, invdeg,
                                          wp + (size_t)l * 4096, bn + (size_t)l * HID,
                                          gam + (size_t)l * HID, bet + (size_t)l * HID,
                                          node_out, xout16, l == 2 ? 1 : 0, l == 0 ? 1 : 0);
    }

    k_pool1<<<N_GRAPHS * 4, 1024, 0, stream>>>(xbb, batch, partial, cnt);
    k_pool2<<<32, 256, 0, stream>>>(partial, cnt, out);
}